// Round 10
// baseline (117.361 us; speedup 1.0000x reference)
//
#include <hip/hip_runtime.h>
#include <hip/hip_fp16.h>
#include <cmath>

#define HWS 4096
#define HWP 2048

typedef _Float16 f16x8 __attribute__((ext_vector_type(8)));
typedef float f32x16 __attribute__((ext_vector_type(16)));
typedef unsigned short ushort_t;
typedef ushort_t ushort8 __attribute__((ext_vector_type(8)));
typedef unsigned int uint_t;

// ---- workspace layout (float offsets) ----
// uhp : [N][HWP][I][OD] uint (fp16 px-pair packed)  16,777,216 uints
// b   : [I][N][HW][O] f32                            2,097,152
// wgt : [I][N][HW][O] f32 (softmax weights c*sinv)   2,097,152
// wpk : packed conv weights fp16 (single term)        409,600 ushorts
static constexpr size_t UHP_OFF = 0;
static constexpr size_t B_OFF   = 16777216ull;
static constexpr size_t WGT_OFF = 18874368ull;
static constexpr size_t WPK_OFF = 20971520ull;

__device__ __forceinline__ float h2f(uint_t u) { return __half2float(__ushort_as_half((ushort_t)u)); }

// ---------------------------------------------------------------------------
// W [i][128oc][16cin][5][5] f32 -> wpack [i][tap][oct4][lane64][8] fp16
// ---------------------------------------------------------------------------
__global__ __launch_bounds__(256) void wpack_kernel(const float* __restrict__ W,
                                                    ushort_t* __restrict__ wp) {
  const int gid = blockIdx.x * 256 + threadIdx.x;  // < 51200
  const int lane = gid & 63;
  int r = gid >> 6;
  const int oct = r & 3; r >>= 2;
  const int tap = r % 25, i = r / 25;
  const int oc = oct * 32 + (lane & 31);
  const int cin0 = (lane >> 5) * 8;
  ushort8 out;
#pragma unroll
  for (int e = 0; e < 8; ++e) {
    float f = W[(((size_t)i * 128 + oc) * 16 + cin0 + e) * 25 + tap];
    out[e] = __half_as_ushort(__float2half(f));
  }
  *(ushort8*)(wp + (size_t)gid * 8) = out;
}

// ---------------------------------------------------------------------------
// MFMA conv v11 (fp16 u x fp16 w, 4 MFMA/tap/wave):
//  - 256-thread blocks (4 waves: wv 0..1 x oh 0..1), 2 output h-rows/block
//  - 8 blocks/CU (LDS 19.6 KB): blocks at DIFFERENT phases co-resident ->
//    one block's staging latency hides under other blocks' MFMA work
//    (the 512-thread config ran whole-CU lockstep: stage, then compute)
//  - weights: 3-slot rotating register buffer, 2-deep prefetch (unchanged)
//  - per-wave tap loop / epilogue byte-identical to v6 -> bit-identical out
// ---------------------------------------------------------------------------
__global__ __launch_bounds__(256, 4) void conv_kernel(const float* __restrict__ u,
                                                      const ushort_t* __restrict__ wp,
                                                      uint_t* __restrict__ uhp) {
  __shared__ ushort_t ut[6 * 68 * 24];   // 19,584 B

  const int tid = threadIdx.x;
  const int lane = tid & 63, wid = tid >> 6;
  const int l31 = lane & 31, half = lane >> 5;
  const int wv = wid >> 1, oh = wid & 1;   // wv 0..1
  const int h0 = blockIdx.x * 2;           // 0..62
  const int q = blockIdx.y;                // q = n*8 + i
  const int i = q & 7, n = q >> 3;

  const ushort_t* wbase = wp + (size_t)i * 51200 + (oh * 2) * 512 + lane * 8;

  // ---- stage input tile: rows h0-2..h0+3, cols 0..63 (+zero halo), f32->fp16
  const float* ub = u + (size_t)q * 16 * HWS;
#pragma unroll
  for (int k = 0; k < 2; ++k) {
    const int unit = tid + k * 256;        // 384 units = 6 rows x 64 cols
    if (unit < 384) {
      const int row = unit >> 6, lane_x = unit & 63;
      const int gh = h0 - 2 + row;
      const bool rowok = (unsigned)gh < 64u;
      const float* src = ub + gh * 64 + lane_x;
      float vals[16];
#pragma unroll
      for (int it = 0; it < 16; ++it)
        vals[it] = rowok ? src[(size_t)it * HWS] : 0.f;
      const int xbase = (row * 68 + lane_x + 2) * 24;
#pragma unroll
      for (int itp = 0; itp < 8; ++itp) {
        uint_t pk = (uint_t)__half_as_ushort(__float2half(vals[2 * itp])) |
                    ((uint_t)__half_as_ushort(__float2half(vals[2 * itp + 1])) << 16);
        *(uint_t*)&ut[xbase + 2 * itp] = pk;
      }
    }
  }
  // halo cols x in {0,1,66,67} are always zero (gx outside [0,64))
  if (tid < 192) {
    const int y = tid >> 5, r = tid & 31;   // y 0..5
    const int xs = r >> 3, cp = r & 7;
    const int x = (xs < 2) ? xs : (64 + xs);   // 0,1,66,67
    *(uint_t*)&ut[(y * 68 + x) * 24 + 2 * cp] = 0u;
  }
  __syncthreads();

  f32x16 acc[2][2];
#pragma unroll
  for (int pt = 0; pt < 2; ++pt)
#pragma unroll
    for (int ot = 0; ot < 2; ++ot)
#pragma unroll
      for (int e = 0; e < 16; ++e) acc[pt][ot][e] = 0.f;

  // ---- weight pipeline: 3-slot rotating buffer, 2-deep prefetch ----
  uint4 wbuf[3][2];
#pragma unroll
  for (int t = 0; t < 2; ++t)
#pragma unroll
    for (int f = 0; f < 2; ++f)
      wbuf[t][f] = *(const uint4*)(wbase + t * 2048 + f * 512);

#pragma unroll
  for (int tap = 0; tap < 25; ++tap) {
    const int kh = tap / 5, kw = tap - kh * 5;
    if (tap + 2 < 25) {
#pragma unroll
      for (int f = 0; f < 2; ++f)
        wbuf[(tap + 2) % 3][f] = *(const uint4*)(wbase + (tap + 2) * 2048 + f * 512);
    }
    f16x8 ah[2];
#pragma unroll
    for (int pt = 0; pt < 2; ++pt)
      ah[pt] = *(const f16x8*)&ut[((wv + kh) * 68 + pt * 32 + l31 + kw) * 24 + half * 8];
#pragma unroll
    for (int ot = 0; ot < 2; ++ot) {
      f16x8 bb = *(const f16x8*)&wbuf[tap % 3][ot];
#pragma unroll
      for (int pt = 0; pt < 2; ++pt)
        acc[pt][ot] = __builtin_amdgcn_mfma_f32_32x32x16_f16(ah[pt], bb, acc[pt][ot], 0, 0, 0);
    }
  }

  // store: px = pt*32 + 8*(r>>2) + 4*half + (r&3); pack fp16 pairs (r even, r+1)
  const int h = h0 + wv;
  uint_t* uhb = uhp + ((size_t)(n * HWP + h * 32) * 8 + i) * 128;
#pragma unroll
  for (int pt = 0; pt < 2; ++pt)
#pragma unroll
    for (int ot = 0; ot < 2; ++ot) {
      const int otg = oh * 2 + ot;
#pragma unroll
      for (int rp = 0; rp < 8; ++rp) {
        const int r = rp * 2;
        const int xp = pt * 16 + 4 * (rp >> 1) + 2 * half + (rp & 1);
        uint_t lo = (uint_t)__half_as_ushort(__float2half(acc[pt][ot][r]));
        uint_t hi = (uint_t)__half_as_ushort(__float2half(acc[pt][ot][r + 1]));
        uhb[(size_t)xp * 1024 + otg * 32 + l31] = lo | (hi << 16);
      }
    }
}

// ---------------------------------------------------------------------------
// Fused softmax + window-sum v2: per (i,n) 32x32 tile, 512 threads.
// Separable 5x5 windows: row-max -> col-max (exact), row-sum -> col-sum
// (reassociation only). Reads b [i][n][hw][o]; writes w = c/sum_c.
// ---------------------------------------------------------------------------
__global__ __launch_bounds__(512) void fsm_kernel(const float* __restrict__ b,
                                                  float* __restrict__ wgt) {
  __shared__ float bt[8][36][36];   // o-major, px (h0-2+y, w0-2+x)   41.5 KB
  __shared__ float m1[40][40];      // per-px o-max (4-halo)           6.4 KB
  __shared__ float rm[40][36];      // row-window max                  5.8 KB
  __shared__ float bm[36][36];      // 5x5 window max                  5.2 KB
  __shared__ float st[36][36];      // per-px sum exp                  5.2 KB
  __shared__ float r5[36][32];      // row-window sum                  4.6 KB
  const int tid = threadIdx.x;
  const int i = blockIdx.z >> 3, n = blockIdx.z & 7;
  const int h0 = blockIdx.y * 32, w0 = blockIdx.x * 32;
  const int inb = i * 8 + n;
  const float* bb = b + (size_t)inb * HWS * 8;

  for (int idx = tid; idx < 1600; idx += 512) {
    const int yy = idx / 40, xx = idx - yy * 40;
    const int h = h0 + yy - 4, w = w0 + xx - 4;
    float v[8];
    if ((unsigned)h < 64u && (unsigned)w < 64u) {
      const float4 a = *(const float4*)(bb + (size_t)(h * 64 + w) * 8);
      const float4 c = *(const float4*)(bb + (size_t)(h * 64 + w) * 8 + 4);
      v[0] = a.x; v[1] = a.y; v[2] = a.z; v[3] = a.w;
      v[4] = c.x; v[5] = c.y; v[6] = c.z; v[7] = c.w;
    } else {
#pragma unroll
      for (int o = 0; o < 8; ++o) v[o] = -INFINITY;
    }
    float m = v[0];
#pragma unroll
    for (int o = 1; o < 8; ++o) m = fmaxf(m, v[o]);
    m1[yy][xx] = m;
    if ((unsigned)(yy - 2) < 36u && (unsigned)(xx - 2) < 36u) {
#pragma unroll
      for (int o = 0; o < 8; ++o) bt[o][yy - 2][xx - 2] = v[o];
    }
  }
  __syncthreads();
  // row-window max: rm[y][xs] = max_{dx} m1[y][xs+dx]
  for (int idx = tid; idx < 1440; idx += 512) {
    const int y = idx / 36, xs = idx - y * 36;
    float m = m1[y][xs];
#pragma unroll
    for (int dx = 1; dx < 5; ++dx) m = fmaxf(m, m1[y][xs + dx]);
    rm[y][xs] = m;
  }
  __syncthreads();
  // col-window max + per-px expsum
  for (int idx = tid; idx < 1296; idx += 512) {
    const int ys = idx / 36, xs = idx - ys * 36;
    float m = rm[ys][xs];
#pragma unroll
    for (int dy = 1; dy < 5; ++dy) m = fmaxf(m, rm[ys + dy][xs]);
    bm[ys][xs] = m;
    float ss = 0.f;
#pragma unroll
    for (int o = 0; o < 8; ++o) ss += __expf(bt[o][ys][xs] - m);
    st[ys][xs] = ss;
  }
  __syncthreads();
  // row-window sum: r5[y][x] = sum_{dx} st[y][x+dx]
  for (int idx = tid; idx < 1152; idx += 512) {
    const int y = idx / 32, x = idx - y * 32;
    float s = st[y][x];
#pragma unroll
    for (int dx = 1; dx < 5; ++dx) s += st[y][x + dx];
    r5[y][x] = s;
  }
  __syncthreads();
  const int tx = tid & 31, ty = tid >> 5;   // ty 0..15
  for (int p = 0; p < 2; ++p) {
    const int y = ty + p * 16, x = tx;
    float sum = r5[y][x];
#pragma unroll
    for (int dy = 1; dy < 5; ++dy) sum += r5[y + dy][x];
    const float rs = 1.0f / sum;
    const float bmv = bm[y + 2][x + 2];
    float w8[8];
#pragma unroll
    for (int o = 0; o < 8; ++o) w8[o] = __expf(bt[o][y + 2][x + 2] - bmv) * rs;
    float* dst = wgt + (size_t)inb * HWS * 8 + (size_t)((h0 + y) * 64 + (w0 + x)) * 8;
    *(float4*)dst = make_float4(w8[0], w8[1], w8[2], w8[3]);
    *(float4*)(dst + 4) = make_float4(w8[4], w8[5], w8[6], w8[7]);
  }
}

// ---------------------------------------------------------------------------
// Route v3: block = 16 px (8 fp16 px-pairs) x 128 od. slot = px-pair,
// quad = od-quad (o = quad>>2, 4-lane d-group reduces via shfl_xor 1,2).
// INIT: analytic r (b==0), b stored. FINAL: writes d_out (LDS transpose).
// Non-final: b-RMW via LDS + coop float4. Intermediate v never written.
// ---------------------------------------------------------------------------
template <int INIT, int FINAL>
__global__ __launch_bounds__(256) void route_kernel(const uint_t* __restrict__ uhp,
                                                    const float* __restrict__ wgt,
                                                    float* __restrict__ b,
                                                    float* __restrict__ out) {
  __shared__ float sm_w[1024];   // wst [i][16px][8o]
  __shared__ float sm_b[2048];   // agt [i][16px][8o] (1024) | vt [128od][16px] (2048)
  const int tid = threadIdx.x;
  const int quad = tid & 31, slot = tid >> 5;
  const int o = quad >> 2;
  const int n = blockIdx.y;
  const int hw0 = blockIdx.x * 16;
  const int hwp = blockIdx.x * 8 + slot;

  if (!INIT) {
    const int li = tid >> 5, r = tid & 31;
    const int pxl = r >> 1, o4 = (r & 1) * 4;
    const float4 wv4 = *(const float4*)(wgt + ((size_t)(li * 8 + n) * HWS + hw0 + pxl) * 8 + o4);
    *(float4*)&sm_w[(li * 16 + pxl) * 8 + o4] = wv4;
    __syncthreads();
  }

  float uv0[8][4], uv1[8][4];
  float pa0[4] = {0.f, 0.f, 0.f, 0.f}, pa1[4] = {0.f, 0.f, 0.f, 0.f};
  const uint_t* up = uhp + (size_t)(n * HWP + hwp) * 1024 + quad * 4;
#pragma unroll
  for (int i = 0; i < 8; ++i) {
    const uint4 q4 = *(const uint4*)(up + i * 128);
    const uint_t qq[4] = {q4.x, q4.y, q4.z, q4.w};
    float w0 = 1.f, w1 = 1.f;
    if (!INIT) {
      w0 = sm_w[(i * 16 + slot * 2) * 8 + o];
      w1 = sm_w[(i * 16 + slot * 2 + 1) * 8 + o];
    }
#pragma unroll
    for (int e = 0; e < 4; ++e) {
      const float a0 = h2f(qq[e] & 0xffffu);
      const float a1 = h2f(qq[e] >> 16);
      uv0[i][e] = a0;
      uv1[i][e] = a1;
      pa0[e] = fmaf(w0, a0, pa0[e]);
      pa1[e] = fmaf(w1, a1, pa1[e]);
    }
  }
  if (INIT) {
    const int hwa = hw0 + slot * 2;
    const int h = hwa >> 6, x = hwa & 63;
    const int nh = min(h + 2, 63) - max(h - 2, 0) + 1;
    const int nw0 = min(x + 2, 63) - max(x - 2, 0) + 1;
    const int nw1 = min(x + 3, 63) - max(x - 1, 0) + 1;
    const float r0 = 1.0f / (float)(8 * nh * nw0);
    const float r1 = 1.0f / (float)(8 * nh * nw1);
#pragma unroll
    for (int e = 0; e < 4; ++e) { pa0[e] *= r0; pa1[e] *= r1; }
  }
  // squash (4-lane group = 16 d-elements of one o)
  float ns0 = pa0[0] * pa0[0] + pa0[1] * pa0[1] + pa0[2] * pa0[2] + pa0[3] * pa0[3];
  float ns1 = pa1[0] * pa1[0] + pa1[1] * pa1[1] + pa1[2] * pa1[2] + pa1[3] * pa1[3];
  ns0 += __shfl_xor(ns0, 1); ns0 += __shfl_xor(ns0, 2);
  ns1 += __shfl_xor(ns1, 1); ns1 += __shfl_xor(ns1, 2);
  const float f0 = ns0 / ((1.f + ns0) * sqrtf(ns0 + 1e-9f));
  const float f1 = ns1 / ((1.f + ns1) * sqrtf(ns1 + 1e-9f));
  float v0[4], v1[4];
#pragma unroll
  for (int e = 0; e < 4; ++e) { v0[e] = f0 * pa0[e]; v1[e] = f1 * pa1[e]; }

  if (FINAL) {
    // vt[od][16px]
#pragma unroll
    for (int e = 0; e < 4; ++e) {
      sm_b[(quad * 4 + e) * 16 + slot * 2] = v0[e];
      sm_b[(quad * 4 + e) * 16 + slot * 2 + 1] = v1[e];
    }
    __syncthreads();
    const int od = tid >> 1, p8 = (tid & 1) * 8;
    float* dst = out + ((size_t)n * 128 + od) * HWS + hw0 + p8;
    const float* src = &sm_b[od * 16 + p8];
    *(float4*)dst = make_float4(src[0], src[1], src[2], src[3]);
    *(float4*)(dst + 4) = make_float4(src[4], src[5], src[6], src[7]);
  } else {
    // agree -> agt
#pragma unroll
    for (int i = 0; i < 8; ++i) {
      float a0 = uv0[i][0] * v0[0] + uv0[i][1] * v0[1] + uv0[i][2] * v0[2] + uv0[i][3] * v0[3];
      float a1 = uv1[i][0] * v1[0] + uv1[i][1] * v1[1] + uv1[i][2] * v1[2] + uv1[i][3] * v1[3];
      a0 += __shfl_xor(a0, 1); a0 += __shfl_xor(a0, 2);
      a1 += __shfl_xor(a1, 1); a1 += __shfl_xor(a1, 2);
      if ((quad & 3) == 0) {
        sm_b[(i * 16 + slot * 2) * 8 + o] = a0;
        sm_b[(i * 16 + slot * 2 + 1) * 8 + o] = a1;
      }
    }
    __syncthreads();
    const int li = tid >> 5, r = tid & 31;
    const int pxl = r >> 1, o4 = (r & 1) * 4;
    float* bp = b + ((size_t)(li * 8 + n) * HWS + hw0 + pxl) * 8 + o4;
    const float4 ag = *(const float4*)&sm_b[(li * 16 + pxl) * 8 + o4];
    if (INIT) {
      *(float4*)bp = ag;
    } else {
      float4 old = *(const float4*)bp;
      *(float4*)bp = make_float4(old.x + ag.x, old.y + ag.y, old.z + ag.z, old.w + ag.w);
    }
  }
}

extern "C" void kernel_launch(void* const* d_in, const int* in_sizes, int n_in,
                              void* d_out, int out_size, void* d_ws, size_t ws_size,
                              hipStream_t stream) {
  const float* u = (const float*)d_in[0];
  const float* W = (const float*)d_in[1];
  float* ws = (float*)d_ws;
  uint_t* uhp = (uint_t*)(ws + UHP_OFF);
  float* b = ws + B_OFF;
  float* wgt = ws + WGT_OFF;
  ushort_t* wpk = (ushort_t*)(ws + WPK_OFF);
  float* out = (float*)d_out;

  wpack_kernel<<<dim3(200), 256, 0, stream>>>(W, wpk);
  conv_kernel<<<dim3(32, 64), 256, 0, stream>>>(u, wpk, uhp);
  // it 0: b == 0 -> analytic weights, writes b
  route_kernel<1, 0><<<dim3(256, 8), 256, 0, stream>>>(uhp, wgt, b, out);
  // it 1
  fsm_kernel<<<dim3(2, 2, 64), 512, 0, stream>>>(b, wgt);
  route_kernel<0, 0><<<dim3(256, 8), 256, 0, stream>>>(uhp, wgt, b, out);
  // it 2 (final): writes d_out directly
  fsm_kernel<<<dim3(2, 2, 64), 512, 0, stream>>>(b, wgt);
  route_kernel<0, 1><<<dim3(256, 8), 256, 0, stream>>>(uhp, wgt, b, out);
}

// Round 11
// 107.405 us; speedup vs baseline: 1.0927x; 1.0927x over previous
//
#include <hip/hip_runtime.h>
#include <hip/hip_fp16.h>
#include <cmath>

#define HWS 4096
#define HWP 2048

typedef _Float16 f16x8 __attribute__((ext_vector_type(8)));
typedef float f32x16 __attribute__((ext_vector_type(16)));
typedef unsigned short ushort_t;
typedef ushort_t ushort8 __attribute__((ext_vector_type(8)));
typedef unsigned int uint_t;

// ---- workspace layout (float offsets) ----
// uhp : [N][HWP][I][OD] uint (fp16 px-pair packed)  16,777,216 uints
// b   : [I][N][HW][O] f32                            2,097,152
// wgt : [I][N][HW][O] f32 (softmax weights c*sinv)   2,097,152
// wpk : packed conv weights fp16 (single term)        409,600 ushorts
static constexpr size_t UHP_OFF = 0;
static constexpr size_t B_OFF   = 16777216ull;
static constexpr size_t WGT_OFF = 18874368ull;
static constexpr size_t WPK_OFF = 20971520ull;

__device__ __forceinline__ float h2f(uint_t u) { return __half2float(__ushort_as_half((ushort_t)u)); }

// ---------------------------------------------------------------------------
// W [i][128oc][16cin][5][5] f32 -> wpack [i][tap][oct4][lane64][8] fp16
// ---------------------------------------------------------------------------
__global__ __launch_bounds__(256) void wpack_kernel(const float* __restrict__ W,
                                                    ushort_t* __restrict__ wp) {
  const int gid = blockIdx.x * 256 + threadIdx.x;  // < 51200
  const int lane = gid & 63;
  int r = gid >> 6;
  const int oct = r & 3; r >>= 2;
  const int tap = r % 25, i = r / 25;
  const int oc = oct * 32 + (lane & 31);
  const int cin0 = (lane >> 5) * 8;
  ushort8 out;
#pragma unroll
  for (int e = 0; e < 8; ++e) {
    float f = W[(((size_t)i * 128 + oc) * 16 + cin0 + e) * 25 + tap];
    out[e] = __half_as_ushort(__float2half(f));
  }
  *(ushort8*)(wp + (size_t)gid * 8) = out;
}

// ---------------------------------------------------------------------------
// MFMA conv v12 = r9's proven v6 body + NT-STORE epilogue (r6-proven -6 us):
//  - 512-thread blocks, 8 waves: wave = (h-row wv, oc-half oh)
//  - weights: 3-slot rotating register buffer, 2 taps of prefetch depth
//  - per tap/wave: 2 ds_read_b128 + 2 dwordx4 w-prefetch + 4 MFMA, no barrier
//  - NT store keeps the 67 MB uhp write stream from turning over per-XCD L2
//    (weight working set stays L2-hit). Route loads stay NORMAL (r6's nt-load
//    was what regressed the routes).
// ---------------------------------------------------------------------------
__global__ __launch_bounds__(512, 4) void conv_kernel(const float* __restrict__ u,
                                                      const ushort_t* __restrict__ wp,
                                                      uint_t* __restrict__ uhp) {
  __shared__ ushort_t ut[8 * 68 * 24];   // 26,112 B

  const int tid = threadIdx.x;
  const int lane = tid & 63, wid = tid >> 6;
  const int l31 = lane & 31, half = lane >> 5;
  const int wv = wid >> 1, oh = wid & 1;
  const int h0 = blockIdx.x * 4;
  const int q = blockIdx.y;            // q = n*8 + i
  const int i = q & 7, n = q >> 3;

  const ushort_t* wbase = wp + (size_t)i * 51200 + (oh * 2) * 512 + lane * 8;

  // ---- stage input tile: rows h0-2..h0+5, cols 0..63 (+zero halo), f32->fp16
  const float* ub = u + (size_t)q * 16 * HWS;
  {
    const int lane_x = tid & 63;         // gx
    const int grp = tid >> 6;            // y = 0..7
    const int gh = h0 - 2 + grp;
    const bool rowok = (unsigned)gh < 64u;
    const float* src = ub + gh * 64 + lane_x;
    float vals[16];
#pragma unroll
    for (int it = 0; it < 16; ++it)
      vals[it] = rowok ? src[(size_t)it * HWS] : 0.f;
    const int xbase = (grp * 68 + lane_x + 2) * 24;
#pragma unroll
    for (int itp = 0; itp < 8; ++itp) {
      uint_t pk = (uint_t)__half_as_ushort(__float2half(vals[2 * itp])) |
                  ((uint_t)__half_as_ushort(__float2half(vals[2 * itp + 1])) << 16);
      *(uint_t*)&ut[xbase + 2 * itp] = pk;
    }
    // halo cols x in {0,1,66,67} are always zero (gx outside [0,64))
    if (tid < 256) {
      const int y = tid >> 5, r = tid & 31;
      const int xs = r >> 3, cp = r & 7;
      const int x = (xs < 2) ? xs : (64 + xs);   // 0,1,66,67
      *(uint_t*)&ut[(y * 68 + x) * 24 + 2 * cp] = 0u;
    }
  }
  __syncthreads();

  f32x16 acc[2][2];
#pragma unroll
  for (int pt = 0; pt < 2; ++pt)
#pragma unroll
    for (int ot = 0; ot < 2; ++ot)
#pragma unroll
      for (int e = 0; e < 16; ++e) acc[pt][ot][e] = 0.f;

  // ---- weight pipeline: 3-slot rotating buffer, 2-deep prefetch ----
  uint4 wbuf[3][2];
#pragma unroll
  for (int t = 0; t < 2; ++t)
#pragma unroll
    for (int f = 0; f < 2; ++f)
      wbuf[t][f] = *(const uint4*)(wbase + t * 2048 + f * 512);

#pragma unroll
  for (int tap = 0; tap < 25; ++tap) {
    const int kh = tap / 5, kw = tap - kh * 5;
    if (tap + 2 < 25) {
#pragma unroll
      for (int f = 0; f < 2; ++f)
        wbuf[(tap + 2) % 3][f] = *(const uint4*)(wbase + (tap + 2) * 2048 + f * 512);
    }
    f16x8 ah[2];
#pragma unroll
    for (int pt = 0; pt < 2; ++pt)
      ah[pt] = *(const f16x8*)&ut[((wv + kh) * 68 + pt * 32 + l31 + kw) * 24 + half * 8];
#pragma unroll
    for (int ot = 0; ot < 2; ++ot) {
      f16x8 bb = *(const f16x8*)&wbuf[tap % 3][ot];
#pragma unroll
      for (int pt = 0; pt < 2; ++pt)
        acc[pt][ot] = __builtin_amdgcn_mfma_f32_32x32x16_f16(ah[pt], bb, acc[pt][ot], 0, 0, 0);
    }
  }

  // store: px = pt*32 + 8*(r>>2) + 4*half + (r&3); pack fp16 pairs (r even, r+1)
  // NON-TEMPORAL: uhp has no read-reuse inside conv; keeps weights L2-hot.
  const int h = h0 + wv;
  uint_t* uhb = uhp + ((size_t)(n * HWP + h * 32) * 8 + i) * 128;
#pragma unroll
  for (int pt = 0; pt < 2; ++pt)
#pragma unroll
    for (int ot = 0; ot < 2; ++ot) {
      const int otg = oh * 2 + ot;
#pragma unroll
      for (int rp = 0; rp < 8; ++rp) {
        const int r = rp * 2;
        const int xp = pt * 16 + 4 * (rp >> 1) + 2 * half + (rp & 1);
        uint_t lo = (uint_t)__half_as_ushort(__float2half(acc[pt][ot][r]));
        uint_t hi = (uint_t)__half_as_ushort(__float2half(acc[pt][ot][r + 1]));
        __builtin_nontemporal_store(lo | (hi << 16), &uhb[(size_t)xp * 1024 + otg * 32 + l31]);
      }
    }
}

// ---------------------------------------------------------------------------
// Fused softmax + window-sum v2: per (i,n) 32x32 tile, 512 threads.
// Separable 5x5 windows: row-max -> col-max (exact), row-sum -> col-sum
// (reassociation only). Reads b [i][n][hw][o]; writes w = c/sum_c.
// ---------------------------------------------------------------------------
__global__ __launch_bounds__(512) void fsm_kernel(const float* __restrict__ b,
                                                  float* __restrict__ wgt) {
  __shared__ float bt[8][36][36];   // o-major, px (h0-2+y, w0-2+x)   41.5 KB
  __shared__ float m1[40][40];      // per-px o-max (4-halo)           6.4 KB
  __shared__ float rm[40][36];      // row-window max                  5.8 KB
  __shared__ float bm[36][36];      // 5x5 window max                  5.2 KB
  __shared__ float st[36][36];      // per-px sum exp                  5.2 KB
  __shared__ float r5[36][32];      // row-window sum                  4.6 KB
  const int tid = threadIdx.x;
  const int i = blockIdx.z >> 3, n = blockIdx.z & 7;
  const int h0 = blockIdx.y * 32, w0 = blockIdx.x * 32;
  const int inb = i * 8 + n;
  const float* bb = b + (size_t)inb * HWS * 8;

  for (int idx = tid; idx < 1600; idx += 512) {
    const int yy = idx / 40, xx = idx - yy * 40;
    const int h = h0 + yy - 4, w = w0 + xx - 4;
    float v[8];
    if ((unsigned)h < 64u && (unsigned)w < 64u) {
      const float4 a = *(const float4*)(bb + (size_t)(h * 64 + w) * 8);
      const float4 c = *(const float4*)(bb + (size_t)(h * 64 + w) * 8 + 4);
      v[0] = a.x; v[1] = a.y; v[2] = a.z; v[3] = a.w;
      v[4] = c.x; v[5] = c.y; v[6] = c.z; v[7] = c.w;
    } else {
#pragma unroll
      for (int o = 0; o < 8; ++o) v[o] = -INFINITY;
    }
    float m = v[0];
#pragma unroll
    for (int o = 1; o < 8; ++o) m = fmaxf(m, v[o]);
    m1[yy][xx] = m;
    if ((unsigned)(yy - 2) < 36u && (unsigned)(xx - 2) < 36u) {
#pragma unroll
      for (int o = 0; o < 8; ++o) bt[o][yy - 2][xx - 2] = v[o];
    }
  }
  __syncthreads();
  // row-window max: rm[y][xs] = max_{dx} m1[y][xs+dx]
  for (int idx = tid; idx < 1440; idx += 512) {
    const int y = idx / 36, xs = idx - y * 36;
    float m = m1[y][xs];
#pragma unroll
    for (int dx = 1; dx < 5; ++dx) m = fmaxf(m, m1[y][xs + dx]);
    rm[y][xs] = m;
  }
  __syncthreads();
  // col-window max + per-px expsum
  for (int idx = tid; idx < 1296; idx += 512) {
    const int ys = idx / 36, xs = idx - ys * 36;
    float m = rm[ys][xs];
#pragma unroll
    for (int dy = 1; dy < 5; ++dy) m = fmaxf(m, rm[ys + dy][xs]);
    bm[ys][xs] = m;
    float ss = 0.f;
#pragma unroll
    for (int o = 0; o < 8; ++o) ss += __expf(bt[o][ys][xs] - m);
    st[ys][xs] = ss;
  }
  __syncthreads();
  // row-window sum: r5[y][x] = sum_{dx} st[y][x+dx]
  for (int idx = tid; idx < 1152; idx += 512) {
    const int y = idx / 32, x = idx - y * 32;
    float s = st[y][x];
#pragma unroll
    for (int dx = 1; dx < 5; ++dx) s += st[y][x + dx];
    r5[y][x] = s;
  }
  __syncthreads();
  const int tx = tid & 31, ty = tid >> 5;   // ty 0..15
  for (int p = 0; p < 2; ++p) {
    const int y = ty + p * 16, x = tx;
    float sum = r5[y][x];
#pragma unroll
    for (int dy = 1; dy < 5; ++dy) sum += r5[y + dy][x];
    const float rs = 1.0f / sum;
    const float bmv = bm[y + 2][x + 2];
    float w8[8];
#pragma unroll
    for (int o = 0; o < 8; ++o) w8[o] = __expf(bt[o][y + 2][x + 2] - bmv) * rs;
    float* dst = wgt + (size_t)inb * HWS * 8 + (size_t)((h0 + y) * 64 + (w0 + x)) * 8;
    *(float4*)dst = make_float4(w8[0], w8[1], w8[2], w8[3]);
    *(float4*)(dst + 4) = make_float4(w8[4], w8[5], w8[6], w8[7]);
  }
}

// ---------------------------------------------------------------------------
// Route v3: block = 16 px (8 fp16 px-pairs) x 128 od. slot = px-pair,
// quad = od-quad (o = quad>>2, 4-lane d-group reduces via shfl_xor 1,2).
// INIT: analytic r (b==0), b stored. FINAL: writes d_out (LDS transpose).
// Non-final: b-RMW via LDS + coop float4. Intermediate v never written.
// (loads NORMAL — r6's nt-load here regressed L2 reuse)
// ---------------------------------------------------------------------------
template <int INIT, int FINAL>
__global__ __launch_bounds__(256) void route_kernel(const uint_t* __restrict__ uhp,
                                                    const float* __restrict__ wgt,
                                                    float* __restrict__ b,
                                                    float* __restrict__ out) {
  __shared__ float sm_w[1024];   // wst [i][16px][8o]
  __shared__ float sm_b[2048];   // agt [i][16px][8o] (1024) | vt [128od][16px] (2048)
  const int tid = threadIdx.x;
  const int quad = tid & 31, slot = tid >> 5;
  const int o = quad >> 2;
  const int n = blockIdx.y;
  const int hw0 = blockIdx.x * 16;
  const int hwp = blockIdx.x * 8 + slot;

  if (!INIT) {
    const int li = tid >> 5, r = tid & 31;
    const int pxl = r >> 1, o4 = (r & 1) * 4;
    const float4 wv4 = *(const float4*)(wgt + ((size_t)(li * 8 + n) * HWS + hw0 + pxl) * 8 + o4);
    *(float4*)&sm_w[(li * 16 + pxl) * 8 + o4] = wv4;
    __syncthreads();
  }

  float uv0[8][4], uv1[8][4];
  float pa0[4] = {0.f, 0.f, 0.f, 0.f}, pa1[4] = {0.f, 0.f, 0.f, 0.f};
  const uint_t* up = uhp + (size_t)(n * HWP + hwp) * 1024 + quad * 4;
#pragma unroll
  for (int i = 0; i < 8; ++i) {
    const uint4 q4 = *(const uint4*)(up + i * 128);
    const uint_t qq[4] = {q4.x, q4.y, q4.z, q4.w};
    float w0 = 1.f, w1 = 1.f;
    if (!INIT) {
      w0 = sm_w[(i * 16 + slot * 2) * 8 + o];
      w1 = sm_w[(i * 16 + slot * 2 + 1) * 8 + o];
    }
#pragma unroll
    for (int e = 0; e < 4; ++e) {
      const float a0 = h2f(qq[e] & 0xffffu);
      const float a1 = h2f(qq[e] >> 16);
      uv0[i][e] = a0;
      uv1[i][e] = a1;
      pa0[e] = fmaf(w0, a0, pa0[e]);
      pa1[e] = fmaf(w1, a1, pa1[e]);
    }
  }
  if (INIT) {
    const int hwa = hw0 + slot * 2;
    const int h = hwa >> 6, x = hwa & 63;
    const int nh = min(h + 2, 63) - max(h - 2, 0) + 1;
    const int nw0 = min(x + 2, 63) - max(x - 2, 0) + 1;
    const int nw1 = min(x + 3, 63) - max(x - 1, 0) + 1;
    const float r0 = 1.0f / (float)(8 * nh * nw0);
    const float r1 = 1.0f / (float)(8 * nh * nw1);
#pragma unroll
    for (int e = 0; e < 4; ++e) { pa0[e] *= r0; pa1[e] *= r1; }
  }
  // squash (4-lane group = 16 d-elements of one o)
  float ns0 = pa0[0] * pa0[0] + pa0[1] * pa0[1] + pa0[2] * pa0[2] + pa0[3] * pa0[3];
  float ns1 = pa1[0] * pa1[0] + pa1[1] * pa1[1] + pa1[2] * pa1[2] + pa1[3] * pa1[3];
  ns0 += __shfl_xor(ns0, 1); ns0 += __shfl_xor(ns0, 2);
  ns1 += __shfl_xor(ns1, 1); ns1 += __shfl_xor(ns1, 2);
  const float f0 = ns0 / ((1.f + ns0) * sqrtf(ns0 + 1e-9f));
  const float f1 = ns1 / ((1.f + ns1) * sqrtf(ns1 + 1e-9f));
  float v0[4], v1[4];
#pragma unroll
  for (int e = 0; e < 4; ++e) { v0[e] = f0 * pa0[e]; v1[e] = f1 * pa1[e]; }

  if (FINAL) {
    // vt[od][16px]
#pragma unroll
    for (int e = 0; e < 4; ++e) {
      sm_b[(quad * 4 + e) * 16 + slot * 2] = v0[e];
      sm_b[(quad * 4 + e) * 16 + slot * 2 + 1] = v1[e];
    }
    __syncthreads();
    const int od = tid >> 1, p8 = (tid & 1) * 8;
    float* dst = out + ((size_t)n * 128 + od) * HWS + hw0 + p8;
    const float* src = &sm_b[od * 16 + p8];
    *(float4*)dst = make_float4(src[0], src[1], src[2], src[3]);
    *(float4*)(dst + 4) = make_float4(src[4], src[5], src[6], src[7]);
  } else {
    // agree -> agt
#pragma unroll
    for (int i = 0; i < 8; ++i) {
      float a0 = uv0[i][0] * v0[0] + uv0[i][1] * v0[1] + uv0[i][2] * v0[2] + uv0[i][3] * v0[3];
      float a1 = uv1[i][0] * v1[0] + uv1[i][1] * v1[1] + uv1[i][2] * v1[2] + uv1[i][3] * v1[3];
      a0 += __shfl_xor(a0, 1); a0 += __shfl_xor(a0, 2);
      a1 += __shfl_xor(a1, 1); a1 += __shfl_xor(a1, 2);
      if ((quad & 3) == 0) {
        sm_b[(i * 16 + slot * 2) * 8 + o] = a0;
        sm_b[(i * 16 + slot * 2 + 1) * 8 + o] = a1;
      }
    }
    __syncthreads();
    const int li = tid >> 5, r = tid & 31;
    const int pxl = r >> 1, o4 = (r & 1) * 4;
    float* bp = b + ((size_t)(li * 8 + n) * HWS + hw0 + pxl) * 8 + o4;
    const float4 ag = *(const float4*)&sm_b[(li * 16 + pxl) * 8 + o4];
    if (INIT) {
      *(float4*)bp = ag;
    } else {
      float4 old = *(const float4*)bp;
      *(float4*)bp = make_float4(old.x + ag.x, old.y + ag.y, old.z + ag.z, old.w + ag.w);
    }
  }
}

extern "C" void kernel_launch(void* const* d_in, const int* in_sizes, int n_in,
                              void* d_out, int out_size, void* d_ws, size_t ws_size,
                              hipStream_t stream) {
  const float* u = (const float*)d_in[0];
  const float* W = (const float*)d_in[1];
  float* ws = (float*)d_ws;
  uint_t* uhp = (uint_t*)(ws + UHP_OFF);
  float* b = ws + B_OFF;
  float* wgt = ws + WGT_OFF;
  ushort_t* wpk = (ushort_t*)(ws + WPK_OFF);
  float* out = (float*)d_out;

  wpack_kernel<<<dim3(200), 256, 0, stream>>>(W, wpk);
  conv_kernel<<<dim3(16, 64), 512, 0, stream>>>(u, wpk, uhp);
  // it 0: b == 0 -> analytic weights, writes b
  route_kernel<1, 0><<<dim3(256, 8), 256, 0, stream>>>(uhp, wgt, b, out);
  // it 1
  fsm_kernel<<<dim3(2, 2, 64), 512, 0, stream>>>(b, wgt);
  route_kernel<0, 0><<<dim3(256, 8), 256, 0, stream>>>(uhp, wgt, b, out);
  // it 2 (final): writes d_out directly
  fsm_kernel<<<dim3(2, 2, 64), 512, 0, stream>>>(b, wgt);
  route_kernel<0, 1><<<dim3(256, 8), 256, 0, stream>>>(uhp, wgt, b, out);
}

// Round 12
// 107.305 us; speedup vs baseline: 1.0937x; 1.0009x over previous
//
#include <hip/hip_runtime.h>
#include <hip/hip_fp16.h>
#include <cmath>

#define HWS 4096
#define HWP 2048

typedef _Float16 f16x8 __attribute__((ext_vector_type(8)));
typedef float f32x16 __attribute__((ext_vector_type(16)));
typedef unsigned short ushort_t;
typedef ushort_t ushort8 __attribute__((ext_vector_type(8)));
typedef unsigned int uint_t;

// ---- workspace layout (float offsets) ----
// uhp : [N][HWP][I][OD] uint (fp16 px-pair packed)  16,777,216 uints
// b   : [I][N][HW][O] f32                            2,097,152
// wgt : [I][N][HW][O] f32 (softmax weights c*sinv)   2,097,152
// wpk : packed conv weights fp16 (single term)        409,600 ushorts
static constexpr size_t UHP_OFF = 0;
static constexpr size_t B_OFF   = 16777216ull;
static constexpr size_t WGT_OFF = 18874368ull;
static constexpr size_t WPK_OFF = 20971520ull;

__device__ __forceinline__ float h2f(uint_t u) { return __half2float(__ushort_as_half((ushort_t)u)); }

// ---------------------------------------------------------------------------
// W [i][128oc][16cin][5][5] f32 -> wpack [i][tap][oct4][lane64][8] fp16
// ---------------------------------------------------------------------------
__global__ __launch_bounds__(256) void wpack_kernel(const float* __restrict__ W,
                                                    ushort_t* __restrict__ wp) {
  const int gid = blockIdx.x * 256 + threadIdx.x;  // < 51200
  const int lane = gid & 63;
  int r = gid >> 6;
  const int oct = r & 3; r >>= 2;
  const int tap = r % 25, i = r / 25;
  const int oc = oct * 32 + (lane & 31);
  const int cin0 = (lane >> 5) * 8;
  ushort8 out;
#pragma unroll
  for (int e = 0; e < 8; ++e) {
    float f = W[(((size_t)i * 128 + oc) * 16 + cin0 + e) * 25 + tap];
    out[e] = __half_as_ushort(__float2half(f));
  }
  *(ushort8*)(wp + (size_t)gid * 8) = out;
}

// ---------------------------------------------------------------------------
// MFMA conv v13 = v12 + 3-deep weight prefetch (r6's best-measured conv cfg):
//  - 512-thread blocks, 8 waves: wave = (h-row wv, oc-half oh)
//  - weights: 4-slot rotating register buffer, 3 taps of prefetch depth
//    (L2 weight latency ~300cyc vs 2-tap MFMA cover ~256cyc was marginal;
//     3-deep gives slack)
//  - NT store keeps the 67 MB uhp write stream from turning over per-XCD L2
//  - per tap/wave: 2 ds_read_b128 + 2 dwordx4 w-prefetch + 4 MFMA, no barrier
// ---------------------------------------------------------------------------
__global__ __launch_bounds__(512, 4) void conv_kernel(const float* __restrict__ u,
                                                      const ushort_t* __restrict__ wp,
                                                      uint_t* __restrict__ uhp) {
  __shared__ ushort_t ut[8 * 68 * 24];   // 26,112 B

  const int tid = threadIdx.x;
  const int lane = tid & 63, wid = tid >> 6;
  const int l31 = lane & 31, half = lane >> 5;
  const int wv = wid >> 1, oh = wid & 1;
  const int h0 = blockIdx.x * 4;
  const int q = blockIdx.y;            // q = n*8 + i
  const int i = q & 7, n = q >> 3;

  const ushort_t* wbase = wp + (size_t)i * 51200 + (oh * 2) * 512 + lane * 8;

  // ---- stage input tile: rows h0-2..h0+5, cols 0..63 (+zero halo), f32->fp16
  const float* ub = u + (size_t)q * 16 * HWS;
  {
    const int lane_x = tid & 63;         // gx
    const int grp = tid >> 6;            // y = 0..7
    const int gh = h0 - 2 + grp;
    const bool rowok = (unsigned)gh < 64u;
    const float* src = ub + gh * 64 + lane_x;
    float vals[16];
#pragma unroll
    for (int it = 0; it < 16; ++it)
      vals[it] = rowok ? src[(size_t)it * HWS] : 0.f;
    const int xbase = (grp * 68 + lane_x + 2) * 24;
#pragma unroll
    for (int itp = 0; itp < 8; ++itp) {
      uint_t pk = (uint_t)__half_as_ushort(__float2half(vals[2 * itp])) |
                  ((uint_t)__half_as_ushort(__float2half(vals[2 * itp + 1])) << 16);
      *(uint_t*)&ut[xbase + 2 * itp] = pk;
    }
    // halo cols x in {0,1,66,67} are always zero (gx outside [0,64))
    if (tid < 256) {
      const int y = tid >> 5, r = tid & 31;
      const int xs = r >> 3, cp = r & 7;
      const int x = (xs < 2) ? xs : (64 + xs);   // 0,1,66,67
      *(uint_t*)&ut[(y * 68 + x) * 24 + 2 * cp] = 0u;
    }
  }
  __syncthreads();

  f32x16 acc[2][2];
#pragma unroll
  for (int pt = 0; pt < 2; ++pt)
#pragma unroll
    for (int ot = 0; ot < 2; ++ot)
#pragma unroll
      for (int e = 0; e < 16; ++e) acc[pt][ot][e] = 0.f;

  // ---- weight pipeline: 4-slot rotating buffer, 3-deep prefetch ----
  uint4 wbuf[4][2];
#pragma unroll
  for (int t = 0; t < 3; ++t)
#pragma unroll
    for (int f = 0; f < 2; ++f)
      wbuf[t][f] = *(const uint4*)(wbase + t * 2048 + f * 512);

#pragma unroll
  for (int tap = 0; tap < 25; ++tap) {
    const int kh = tap / 5, kw = tap - kh * 5;
    if (tap + 3 < 25) {
#pragma unroll
      for (int f = 0; f < 2; ++f)
        wbuf[(tap + 3) & 3][f] = *(const uint4*)(wbase + (tap + 3) * 2048 + f * 512);
    }
    f16x8 ah[2];
#pragma unroll
    for (int pt = 0; pt < 2; ++pt)
      ah[pt] = *(const f16x8*)&ut[((wv + kh) * 68 + pt * 32 + l31 + kw) * 24 + half * 8];
#pragma unroll
    for (int ot = 0; ot < 2; ++ot) {
      f16x8 bb = *(const f16x8*)&wbuf[tap & 3][ot];
#pragma unroll
      for (int pt = 0; pt < 2; ++pt)
        acc[pt][ot] = __builtin_amdgcn_mfma_f32_32x32x16_f16(ah[pt], bb, acc[pt][ot], 0, 0, 0);
    }
  }

  // store: px = pt*32 + 8*(r>>2) + 4*half + (r&3); pack fp16 pairs (r even, r+1)
  // NON-TEMPORAL: uhp has no read-reuse inside conv; keeps weights L2-hot.
  const int h = h0 + wv;
  uint_t* uhb = uhp + ((size_t)(n * HWP + h * 32) * 8 + i) * 128;
#pragma unroll
  for (int pt = 0; pt < 2; ++pt)
#pragma unroll
    for (int ot = 0; ot < 2; ++ot) {
      const int otg = oh * 2 + ot;
#pragma unroll
      for (int rp = 0; rp < 8; ++rp) {
        const int r = rp * 2;
        const int xp = pt * 16 + 4 * (rp >> 1) + 2 * half + (rp & 1);
        uint_t lo = (uint_t)__half_as_ushort(__float2half(acc[pt][ot][r]));
        uint_t hi = (uint_t)__half_as_ushort(__float2half(acc[pt][ot][r + 1]));
        __builtin_nontemporal_store(lo | (hi << 16), &uhb[(size_t)xp * 1024 + otg * 32 + l31]);
      }
    }
}

// ---------------------------------------------------------------------------
// Fused softmax + window-sum v2: per (i,n) 32x32 tile, 512 threads.
// Separable 5x5 windows: row-max -> col-max (exact), row-sum -> col-sum
// (reassociation only). Reads b [i][n][hw][o]; writes w = c/sum_c.
// ---------------------------------------------------------------------------
__global__ __launch_bounds__(512) void fsm_kernel(const float* __restrict__ b,
                                                  float* __restrict__ wgt) {
  __shared__ float bt[8][36][36];   // o-major, px (h0-2+y, w0-2+x)   41.5 KB
  __shared__ float m1[40][40];      // per-px o-max (4-halo)           6.4 KB
  __shared__ float rm[40][36];      // row-window max                  5.8 KB
  __shared__ float bm[36][36];      // 5x5 window max                  5.2 KB
  __shared__ float st[36][36];      // per-px sum exp                  5.2 KB
  __shared__ float r5[36][32];      // row-window sum                  4.6 KB
  const int tid = threadIdx.x;
  const int i = blockIdx.z >> 3, n = blockIdx.z & 7;
  const int h0 = blockIdx.y * 32, w0 = blockIdx.x * 32;
  const int inb = i * 8 + n;
  const float* bb = b + (size_t)inb * HWS * 8;

  for (int idx = tid; idx < 1600; idx += 512) {
    const int yy = idx / 40, xx = idx - yy * 40;
    const int h = h0 + yy - 4, w = w0 + xx - 4;
    float v[8];
    if ((unsigned)h < 64u && (unsigned)w < 64u) {
      const float4 a = *(const float4*)(bb + (size_t)(h * 64 + w) * 8);
      const float4 c = *(const float4*)(bb + (size_t)(h * 64 + w) * 8 + 4);
      v[0] = a.x; v[1] = a.y; v[2] = a.z; v[3] = a.w;
      v[4] = c.x; v[5] = c.y; v[6] = c.z; v[7] = c.w;
    } else {
#pragma unroll
      for (int o = 0; o < 8; ++o) v[o] = -INFINITY;
    }
    float m = v[0];
#pragma unroll
    for (int o = 1; o < 8; ++o) m = fmaxf(m, v[o]);
    m1[yy][xx] = m;
    if ((unsigned)(yy - 2) < 36u && (unsigned)(xx - 2) < 36u) {
#pragma unroll
      for (int o = 0; o < 8; ++o) bt[o][yy - 2][xx - 2] = v[o];
    }
  }
  __syncthreads();
  // row-window max: rm[y][xs] = max_{dx} m1[y][xs+dx]
  for (int idx = tid; idx < 1440; idx += 512) {
    const int y = idx / 36, xs = idx - y * 36;
    float m = m1[y][xs];
#pragma unroll
    for (int dx = 1; dx < 5; ++dx) m = fmaxf(m, m1[y][xs + dx]);
    rm[y][xs] = m;
  }
  __syncthreads();
  // col-window max + per-px expsum
  for (int idx = tid; idx < 1296; idx += 512) {
    const int ys = idx / 36, xs = idx - ys * 36;
    float m = rm[ys][xs];
#pragma unroll
    for (int dy = 1; dy < 5; ++dy) m = fmaxf(m, rm[ys + dy][xs]);
    bm[ys][xs] = m;
    float ss = 0.f;
#pragma unroll
    for (int o = 0; o < 8; ++o) ss += __expf(bt[o][ys][xs] - m);
    st[ys][xs] = ss;
  }
  __syncthreads();
  // row-window sum: r5[y][x] = sum_{dx} st[y][x+dx]
  for (int idx = tid; idx < 1152; idx += 512) {
    const int y = idx / 32, x = idx - y * 32;
    float s = st[y][x];
#pragma unroll
    for (int dx = 1; dx < 5; ++dx) s += st[y][x + dx];
    r5[y][x] = s;
  }
  __syncthreads();
  const int tx = tid & 31, ty = tid >> 5;   // ty 0..15
  for (int p = 0; p < 2; ++p) {
    const int y = ty + p * 16, x = tx;
    float sum = r5[y][x];
#pragma unroll
    for (int dy = 1; dy < 5; ++dy) sum += r5[y + dy][x];
    const float rs = 1.0f / sum;
    const float bmv = bm[y + 2][x + 2];
    float w8[8];
#pragma unroll
    for (int o = 0; o < 8; ++o) w8[o] = __expf(bt[o][y + 2][x + 2] - bmv) * rs;
    float* dst = wgt + (size_t)inb * HWS * 8 + (size_t)((h0 + y) * 64 + (w0 + x)) * 8;
    *(float4*)dst = make_float4(w8[0], w8[1], w8[2], w8[3]);
    *(float4*)(dst + 4) = make_float4(w8[4], w8[5], w8[6], w8[7]);
  }
}

// ---------------------------------------------------------------------------
// Route v3: block = 16 px (8 fp16 px-pairs) x 128 od. slot = px-pair,
// quad = od-quad (o = quad>>2, 4-lane d-group reduces via shfl_xor 1,2).
// INIT: analytic r (b==0), b stored. FINAL: writes d_out (LDS transpose).
// Non-final: b-RMW via LDS + coop float4. Intermediate v never written.
// (loads NORMAL — r6's nt-load here regressed L2 reuse)
// ---------------------------------------------------------------------------
template <int INIT, int FINAL>
__global__ __launch_bounds__(256) void route_kernel(const uint_t* __restrict__ uhp,
                                                    const float* __restrict__ wgt,
                                                    float* __restrict__ b,
                                                    float* __restrict__ out) {
  __shared__ float sm_w[1024];   // wst [i][16px][8o]
  __shared__ float sm_b[2048];   // agt [i][16px][8o] (1024) | vt [128od][16px] (2048)
  const int tid = threadIdx.x;
  const int quad = tid & 31, slot = tid >> 5;
  const int o = quad >> 2;
  const int n = blockIdx.y;
  const int hw0 = blockIdx.x * 16;
  const int hwp = blockIdx.x * 8 + slot;

  if (!INIT) {
    const int li = tid >> 5, r = tid & 31;
    const int pxl = r >> 1, o4 = (r & 1) * 4;
    const float4 wv4 = *(const float4*)(wgt + ((size_t)(li * 8 + n) * HWS + hw0 + pxl) * 8 + o4);
    *(float4*)&sm_w[(li * 16 + pxl) * 8 + o4] = wv4;
    __syncthreads();
  }

  float uv0[8][4], uv1[8][4];
  float pa0[4] = {0.f, 0.f, 0.f, 0.f}, pa1[4] = {0.f, 0.f, 0.f, 0.f};
  const uint_t* up = uhp + (size_t)(n * HWP + hwp) * 1024 + quad * 4;
#pragma unroll
  for (int i = 0; i < 8; ++i) {
    const uint4 q4 = *(const uint4*)(up + i * 128);
    const uint_t qq[4] = {q4.x, q4.y, q4.z, q4.w};
    float w0 = 1.f, w1 = 1.f;
    if (!INIT) {
      w0 = sm_w[(i * 16 + slot * 2) * 8 + o];
      w1 = sm_w[(i * 16 + slot * 2 + 1) * 8 + o];
    }
#pragma unroll
    for (int e = 0; e < 4; ++e) {
      const float a0 = h2f(qq[e] & 0xffffu);
      const float a1 = h2f(qq[e] >> 16);
      uv0[i][e] = a0;
      uv1[i][e] = a1;
      pa0[e] = fmaf(w0, a0, pa0[e]);
      pa1[e] = fmaf(w1, a1, pa1[e]);
    }
  }
  if (INIT) {
    const int hwa = hw0 + slot * 2;
    const int h = hwa >> 6, x = hwa & 63;
    const int nh = min(h + 2, 63) - max(h - 2, 0) + 1;
    const int nw0 = min(x + 2, 63) - max(x - 2, 0) + 1;
    const int nw1 = min(x + 3, 63) - max(x - 1, 0) + 1;
    const float r0 = 1.0f / (float)(8 * nh * nw0);
    const float r1 = 1.0f / (float)(8 * nh * nw1);
#pragma unroll
    for (int e = 0; e < 4; ++e) { pa0[e] *= r0; pa1[e] *= r1; }
  }
  // squash (4-lane group = 16 d-elements of one o)
  float ns0 = pa0[0] * pa0[0] + pa0[1] * pa0[1] + pa0[2] * pa0[2] + pa0[3] * pa0[3];
  float ns1 = pa1[0] * pa1[0] + pa1[1] * pa1[1] + pa1[2] * pa1[2] + pa1[3] * pa1[3];
  ns0 += __shfl_xor(ns0, 1); ns0 += __shfl_xor(ns0, 2);
  ns1 += __shfl_xor(ns1, 1); ns1 += __shfl_xor(ns1, 2);
  const float f0 = ns0 / ((1.f + ns0) * sqrtf(ns0 + 1e-9f));
  const float f1 = ns1 / ((1.f + ns1) * sqrtf(ns1 + 1e-9f));
  float v0[4], v1[4];
#pragma unroll
  for (int e = 0; e < 4; ++e) { v0[e] = f0 * pa0[e]; v1[e] = f1 * pa1[e]; }

  if (FINAL) {
    // vt[od][16px]
#pragma unroll
    for (int e = 0; e < 4; ++e) {
      sm_b[(quad * 4 + e) * 16 + slot * 2] = v0[e];
      sm_b[(quad * 4 + e) * 16 + slot * 2 + 1] = v1[e];
    }
    __syncthreads();
    const int od = tid >> 1, p8 = (tid & 1) * 8;
    float* dst = out + ((size_t)n * 128 + od) * HWS + hw0 + p8;
    const float* src = &sm_b[od * 16 + p8];
    *(float4*)dst = make_float4(src[0], src[1], src[2], src[3]);
    *(float4*)(dst + 4) = make_float4(src[4], src[5], src[6], src[7]);
  } else {
    // agree -> agt
#pragma unroll
    for (int i = 0; i < 8; ++i) {
      float a0 = uv0[i][0] * v0[0] + uv0[i][1] * v0[1] + uv0[i][2] * v0[2] + uv0[i][3] * v0[3];
      float a1 = uv1[i][0] * v1[0] + uv1[i][1] * v1[1] + uv1[i][2] * v1[2] + uv1[i][3] * v1[3];
      a0 += __shfl_xor(a0, 1); a0 += __shfl_xor(a0, 2);
      a1 += __shfl_xor(a1, 1); a1 += __shfl_xor(a1, 2);
      if ((quad & 3) == 0) {
        sm_b[(i * 16 + slot * 2) * 8 + o] = a0;
        sm_b[(i * 16 + slot * 2 + 1) * 8 + o] = a1;
      }
    }
    __syncthreads();
    const int li = tid >> 5, r = tid & 31;
    const int pxl = r >> 1, o4 = (r & 1) * 4;
    float* bp = b + ((size_t)(li * 8 + n) * HWS + hw0 + pxl) * 8 + o4;
    const float4 ag = *(const float4*)&sm_b[(li * 16 + pxl) * 8 + o4];
    if (INIT) {
      *(float4*)bp = ag;
    } else {
      float4 old = *(const float4*)bp;
      *(float4*)bp = make_float4(old.x + ag.x, old.y + ag.y, old.z + ag.z, old.w + ag.w);
    }
  }
}

extern "C" void kernel_launch(void* const* d_in, const int* in_sizes, int n_in,
                              void* d_out, int out_size, void* d_ws, size_t ws_size,
                              hipStream_t stream) {
  const float* u = (const float*)d_in[0];
  const float* W = (const float*)d_in[1];
  float* ws = (float*)d_ws;
  uint_t* uhp = (uint_t*)(ws + UHP_OFF);
  float* b = ws + B_OFF;
  float* wgt = ws + WGT_OFF;
  ushort_t* wpk = (ushort_t*)(ws + WPK_OFF);
  float* out = (float*)d_out;

  wpack_kernel<<<dim3(200), 256, 0, stream>>>(W, wpk);
  conv_kernel<<<dim3(16, 64), 512, 0, stream>>>(u, wpk, uhp);
  // it 0: b == 0 -> analytic weights, writes b
  route_kernel<1, 0><<<dim3(256, 8), 256, 0, stream>>>(uhp, wgt, b, out);
  // it 1
  fsm_kernel<<<dim3(2, 2, 64), 512, 0, stream>>>(b, wgt);
  route_kernel<0, 0><<<dim3(256, 8), 256, 0, stream>>>(uhp, wgt, b, out);
  // it 2 (final): writes d_out directly
  fsm_kernel<<<dim3(2, 2, 64), 512, 0, stream>>>(b, wgt);
  route_kernel<0, 1><<<dim3(256, 8), 256, 0, stream>>>(uhp, wgt, b, out);
}